// Round 2
// baseline (703.586 us; speedup 1.0000x reference)
//
#include <hip/hip_runtime.h>
#include <hip/hip_bf16.h>
#include <stdint.h>

#define NN 4096
#define KK 4096
#define EPSV 1e-7f
#define NEGV -1e9f

typedef short short8 __attribute__((ext_vector_type(8)));
typedef __bf16 bf16x8 __attribute__((ext_vector_type(8)));
typedef float floatx4 __attribute__((ext_vector_type(4)));
typedef int int4v __attribute__((ext_vector_type(4)));

__device__ __forceinline__ float bf2f(short s) {
    union { unsigned u; float f; } c;
    c.u = ((unsigned)(unsigned short)s) << 16;
    return c.f;
}
__device__ __forceinline__ short f2bf(float f) {
    union { float f; unsigned u; } c;
    c.f = f;
    unsigned r = (c.u + 0x7fffu + ((c.u >> 16) & 1u)) >> 16;
    return (short)r;
}

// nsq[j] = sum_i x[i][j]^2   (column sums of squares; nsq pre-zeroed)
__global__ __launch_bounds__(256) void col_norm_sq(const float* __restrict__ x,
                                                   float* __restrict__ nsq) {
    const int col = blockIdx.x * 256 + threadIdx.x;
    const int row0 = blockIdx.y * 128;
    float s = 0.f;
    for (int r = 0; r < 128; ++r) {
        float v = x[(size_t)(row0 + r) * NN + col];
        s = fmaf(v, v, s);
    }
    atomicAdd(&nsq[col], s);
}

// xb = bf16(x) row-major; xbT = bf16(x^T)
__global__ __launch_bounds__(256) void cast_transpose(const float* __restrict__ x,
                                                      short* __restrict__ xb,
                                                      short* __restrict__ xbT) {
    __shared__ short tile[64][66];  // +2 shorts pad -> conflict-free
    const int tx = threadIdx.x;     // 0..63
    const int ty = threadIdx.y;     // 0..3
    const int cb = blockIdx.x * 64;
    const int rb = blockIdx.y * 64;
#pragma unroll
    for (int i = 0; i < 16; ++i) {
        int r = ty + i * 4;
        short b = f2bf(x[(size_t)(rb + r) * NN + cb + tx]);
        xb[(size_t)(rb + r) * NN + cb + tx] = b;
        tile[r][tx] = b;
    }
    __syncthreads();
#pragma unroll
    for (int i = 0; i < 16; ++i) {
        int r = ty + i * 4;
        xbT[(size_t)(cb + r) * NN + rb + tx] = tile[tx][r];
    }
}

// NT GEMM: C[i][j] = sum_k A[i][k] * Bt[j][k], bf16 [4096][4096].
// 128x128 tile, BK=32, 4 waves 2x2, 64x64/wave via 4x4 mfma_f32_16x16x32_bf16.
// Staging: global->REGISTER prefetch issued before the MFMA phase, then
// ds_write after the barrier -- the vmcnt wait lands after ~500 cyc of
// compute instead of immediately (R1 exposed full load latency every iter:
// global_load_lds + immediate __syncthreads -> vmcnt(0) drain, MfmaUtil 18%).
// LDS layout: granule g=[q=k/8][row] of 8 bf16, conflict-free b128 ops.
template <int MODE>
__global__ __launch_bounds__(256, 4) void gemm_nt(const short* __restrict__ A,
                                                  const short* __restrict__ Bt,
                                                  void* __restrict__ Cout,
                                                  const float* __restrict__ nsq,
                                                  const float* __restrict__ adj,
                                                  const float* __restrict__ betaPtr) {
    __shared__ __align__(16) short ldsA[4096];  // 4 quads * 128 rows * 8
    __shared__ __align__(16) short ldsB[4096];

    const int t = threadIdx.x;
    const int rowTile = blockIdx.y * 128;
    const int colTile = blockIdx.x * 128;

    floatx4 acc[4][4];
#pragma unroll
    for (int s = 0; s < 4; ++s)
#pragma unroll
        for (int n = 0; n < 4; ++n) acc[s][n] = (floatx4){0.f, 0.f, 0.f, 0.f};

    const int lane = t & 63;
    const int w = t >> 6;
    const int wm = (w >> 1) * 64;
    const int wn = (w & 1) * 64;
    const int q = lane >> 4;     // k-quad 0..3
    const int rsub = lane & 15;  // row/col within 16

    // staging granule g (0..511) = [q=g>>7][row=g&127]; thread t: g=t and g=256+t
    const int q0 = t >> 7, r0 = t & 127;
    const int q1 = (256 + t) >> 7, r1 = (256 + t) & 127;
    const short* a0 = A + (size_t)(rowTile + r0) * KK + q0 * 8;
    const short* a1 = A + (size_t)(rowTile + r1) * KK + q1 * 8;
    const short* b0 = Bt + (size_t)(colTile + r0) * KK + q0 * 8;
    const short* b1 = Bt + (size_t)(colTile + r1) * KK + q1 * 8;
    short* la0 = ldsA + (size_t)t * 8;
    short* la1 = ldsA + (size_t)(256 + t) * 8;
    short* lb0 = ldsB + (size_t)t * 8;
    short* lb1 = ldsB + (size_t)(256 + t) * 8;

    // preload tile 0 into registers
    int4v ra0 = *(const int4v*)a0;
    int4v ra1 = *(const int4v*)a1;
    int4v rb0 = *(const int4v*)b0;
    int4v rb1 = *(const int4v*)b1;

    for (int kb = 0; kb < KK; kb += 32) {
        __syncthreads();  // all waves done reading LDS from previous iter
        *(int4v*)la0 = ra0;  // vmcnt wait here targets loads issued a full
        *(int4v*)la1 = ra1;  // compute-phase ago -> near-zero stall
        *(int4v*)lb0 = rb0;
        *(int4v*)lb1 = rb1;
        __syncthreads();

        if (kb + 32 < KK) {  // issue next tile's loads; consumed next iter
            ra0 = *(const int4v*)(a0 + kb + 32);
            ra1 = *(const int4v*)(a1 + kb + 32);
            rb0 = *(const int4v*)(b0 + kb + 32);
            rb1 = *(const int4v*)(b1 + kb + 32);
        }

        short8 af[4], bq[4];
#pragma unroll
        for (int s = 0; s < 4; ++s) {
            af[s] = *(const short8*)(ldsA + ((size_t)q * 128 + wm + s * 16 + rsub) * 8);
            bq[s] = *(const short8*)(ldsB + ((size_t)q * 128 + wn + s * 16 + rsub) * 8);
        }
#pragma unroll
        for (int s = 0; s < 4; ++s)
#pragma unroll
            for (int n = 0; n < 4; ++n)
                acc[s][n] = __builtin_amdgcn_mfma_f32_16x16x32_bf16(
                    __builtin_bit_cast(bf16x8, af[s]), __builtin_bit_cast(bf16x8, bq[n]),
                    acc[s][n], 0, 0, 0);
    }

    // C/D layout: col = lane&15, row = (lane>>4)*4 + reg
    const int rowBase = rowTile + wm + q * 4;
    const int colBase = colTile + wn + rsub;
    if constexpr (MODE == 1) {
        const float beta = *betaPtr;
        short* Sc = (short*)Cout;
        float ncol[4];
#pragma unroll
        for (int n = 0; n < 4; ++n) ncol[n] = sqrtf(nsq[colBase + n * 16]);
#pragma unroll
        for (int s = 0; s < 4; ++s) {
#pragma unroll
            for (int r = 0; r < 4; ++r) {
                const int row = rowBase + s * 16 + r;
                const float nr = sqrtf(nsq[row]);
#pragma unroll
                for (int n = 0; n < 4; ++n) {
                    const int col = colBase + n * 16;
                    float v = acc[s][n][r] * beta / (nr * ncol[n] + EPSV);
                    v += (1.f - adj[(size_t)row * NN + col]) * NEGV;
                    Sc[(size_t)row * NN + col] = f2bf(v);
                }
            }
        }
    } else {
        float* O = (float*)Cout;
#pragma unroll
        for (int s = 0; s < 4; ++s)
#pragma unroll
            for (int r = 0; r < 4; ++r) {
                const int row = rowBase + s * 16 + r;
#pragma unroll
                for (int n = 0; n < 4; ++n)
                    O[(size_t)row * NN + colBase + n * 16] = acc[s][n][r];
            }
    }
}

// In-place row softmax over 4096 bf16 logits; masked entries (-1e9) -> exp = 0.
__global__ __launch_bounds__(256) void softmax_rows(short* __restrict__ S) {
    const int t = threadIdx.x;
    short* rp = S + (size_t)blockIdx.x * NN;
    short8 v0 = ((const short8*)rp)[2 * t];
    short8 v1 = ((const short8*)rp)[2 * t + 1];
    float f[16];
#pragma unroll
    for (int i = 0; i < 8; ++i) {
        f[i] = bf2f(v0[i]);
        f[8 + i] = bf2f(v1[i]);
    }
    float m = f[0];
#pragma unroll
    for (int i = 1; i < 16; ++i) m = fmaxf(m, f[i]);
#pragma unroll
    for (int off = 32; off > 0; off >>= 1) m = fmaxf(m, __shfl_xor(m, off, 64));
    __shared__ float redm[4], reds[4];
    if ((t & 63) == 0) redm[t >> 6] = m;
    __syncthreads();
    m = fmaxf(fmaxf(redm[0], redm[1]), fmaxf(redm[2], redm[3]));
    float sum = 0.f;
#pragma unroll
    for (int i = 0; i < 16; ++i) {
        f[i] = __expf(f[i] - m);
        sum += f[i];
    }
#pragma unroll
    for (int off = 32; off > 0; off >>= 1) sum += __shfl_xor(sum, off, 64);
    if ((t & 63) == 0) reds[t >> 6] = sum;
    __syncthreads();
    sum = reds[0] + reds[1] + reds[2] + reds[3];
    const float rl = 1.f / sum;
    short8 o0, o1;
#pragma unroll
    for (int i = 0; i < 8; ++i) {
        o0[i] = f2bf(f[i] * rl);
        o1[i] = f2bf(f[8 + i] * rl);
    }
    ((short8*)rp)[2 * t] = o0;
    ((short8*)rp)[2 * t + 1] = o1;
}

extern "C" void kernel_launch(void* const* d_in, const int* in_sizes, int n_in,
                              void* d_out, int out_size, void* d_ws, size_t ws_size,
                              hipStream_t stream) {
    const float* x = (const float*)d_in[0];
    const float* adj = (const float*)d_in[1];
    const float* beta = (const float*)d_in[2];

    const size_t MB32 = (size_t)32 * 1024 * 1024;
    if (ws_size < 3 * MB32 + NN * sizeof(float)) return;  // need ~96 MB scratch

    char* ws = (char*)d_ws;
    short* xb = (short*)ws;               // bf16 x          [4096][4096]
    short* xbT = (short*)(ws + MB32);     // bf16 x^T        [4096][4096]
    short* S = (short*)(ws + 2 * MB32);   // bf16 logits / P [4096][4096]
    float* nsq = (float*)(ws + 3 * MB32); // column sumsq    [4096]

    hipMemsetAsync(nsq, 0, NN * sizeof(float), stream);
    col_norm_sq<<<dim3(16, 32), 256, 0, stream>>>(x, nsq);
    cast_transpose<<<dim3(64, 64), dim3(64, 4), 0, stream>>>(x, xb, xbT);
    gemm_nt<1><<<dim3(32, 32), 256, 0, stream>>>(xb, xb, S, nsq, adj, beta);
    softmax_rows<<<NN, 256, 0, stream>>>(S);
    gemm_nt<2><<<dim3(32, 32), 256, 0, stream>>>(S, xbT, d_out, nullptr, nullptr, nullptr);
}

// Round 3
// 482.945 us; speedup vs baseline: 1.4569x; 1.4569x over previous
//
#include <hip/hip_runtime.h>
#include <hip/hip_bf16.h>
#include <stdint.h>

#define NN 4096
#define KK 4096
#define EPSV 1e-7f
#define NEGV -1e9f

typedef short short8 __attribute__((ext_vector_type(8)));
typedef __bf16 bf16x8 __attribute__((ext_vector_type(8)));
typedef float floatx4 __attribute__((ext_vector_type(4)));

__device__ __forceinline__ float bf2f(short s) {
    union { unsigned u; float f; } c;
    c.u = ((unsigned)(unsigned short)s) << 16;
    return c.f;
}
__device__ __forceinline__ short f2bf(float f) {
    union { float f; unsigned u; } c;
    c.f = f;
    unsigned r = (c.u + 0x7fffu + ((c.u >> 16) & 1u)) >> 16;
    return (short)r;
}

// nsq[j] = sum_i x[i][j]^2   (column sums of squares; nsq pre-zeroed)
__global__ __launch_bounds__(256) void col_norm_sq(const float* __restrict__ x,
                                                   float* __restrict__ nsq) {
    const int col = blockIdx.x * 256 + threadIdx.x;
    const int row0 = blockIdx.y * 128;
    float s = 0.f;
    for (int r = 0; r < 128; ++r) {
        float v = x[(size_t)(row0 + r) * NN + col];
        s = fmaf(v, v, s);
    }
    atomicAdd(&nsq[col], s);
}

// xb = bf16(x) row-major; xbT = bf16(x^T)
__global__ __launch_bounds__(256) void cast_transpose(const float* __restrict__ x,
                                                      short* __restrict__ xb,
                                                      short* __restrict__ xbT) {
    __shared__ short tile[64][66];  // +2 shorts pad -> conflict-free
    const int tx = threadIdx.x;     // 0..63
    const int ty = threadIdx.y;     // 0..3
    const int cb = blockIdx.x * 64;
    const int rb = blockIdx.y * 64;
#pragma unroll
    for (int i = 0; i < 16; ++i) {
        int r = ty + i * 4;
        short b = f2bf(x[(size_t)(rb + r) * NN + cb + tx]);
        xb[(size_t)(rb + r) * NN + cb + tx] = b;
        tile[r][tx] = b;
    }
    __syncthreads();
#pragma unroll
    for (int i = 0; i < 16; ++i) {
        int r = ty + i * 4;
        xbT[(size_t)(cb + r) * NN + rb + tx] = tile[tx][r];
    }
}

// NT GEMM: C[i][j] = sum_k A[i][k] * Bt[j][k], bf16 [4096][4096].
// 128x128 tile, BK=32, 4 waves 2x2, 64x64/wave via 4x4 mfma_f32_16x16x32_bf16.
//
// R3 staging (the R1/R2 bug was here): LDS layout is [row][kchunk] so each
// glds wave-op covers 16 rows x 64 CONTIGUOUS bytes (4 lanes/64B line, 16
// lines/op) instead of 64 distinct 8KB-strided lines/op. Chunk is stored at
// swizzled position c = q ^ ((row>>1)&3) to break the stride-64B 8-way bank
// conflict on ds_read (16 lanes -> 8 bank-quads x2 = free 2-way). The swizzle
// is realized on the GLOBAL side: lane i fetches chunk (i&3)^((i>>3)&3) of
// row i>>2 (same 64B line, permuted -> coalescing preserved).
// Double-buffered LDS + one barrier/iter: the barrier's vmcnt(0) drain hits
// loads issued a full compute-phase earlier.
template <int MODE>
__global__ __launch_bounds__(256, 4) void gemm_nt(const short* __restrict__ A,
                                                  const short* __restrict__ Bt,
                                                  void* __restrict__ Cout,
                                                  const float* __restrict__ nsq,
                                                  const float* __restrict__ adj,
                                                  const float* __restrict__ betaPtr) {
    // [buf][A: 4096 shorts | B: 4096 shorts]
    __shared__ __align__(16) short lds[2][8192];

    const int t = threadIdx.x;
    const int rowTile = blockIdx.y * 128;
    const int colTile = blockIdx.x * 128;

    floatx4 acc[4][4];
#pragma unroll
    for (int s = 0; s < 4; ++s)
#pragma unroll
        for (int n = 0; n < 4; ++n) acc[s][n] = (floatx4){0.f, 0.f, 0.f, 0.f};

    const int lane = t & 63;
    const int w = t >> 6;
    const int wm = (w >> 1) * 64;
    const int wn = (w & 1) * 64;
    const int q = lane >> 4;     // k-chunk 0..3 (MFMA operand)
    const int rsub = lane & 15;  // row/col within 16

    // ---- staging map: wave w stages rows [w*32, w*32+32) of A and of Bt,
    // two wave-ops each (16 rows/op). lane i -> row base+ (i>>2),
    // global chunk qsw = (i&3)^((i>>3)&3), LDS pos = wave-base + i*16B.
    const int qsw = (lane & 3) ^ ((lane >> 3) & 3);
    const int srow = w * 32 + (lane >> 2);
    const short* gA0 = A + (size_t)(rowTile + srow) * KK + qsw * 8;
    const short* gA1 = A + (size_t)(rowTile + srow + 16) * KK + qsw * 8;
    const short* gB0 = Bt + (size_t)(colTile + srow) * KK + qsw * 8;
    const short* gB1 = Bt + (size_t)(colTile + srow + 16) * KK + qsw * 8;
    const int ldsOffA0 = (w * 128 + lane) * 8;         // shorts
    const int ldsOffA1 = (w * 128 + 64 + lane) * 8;
    const int ldsOffB0 = 4096 + (w * 128 + lane) * 8;
    const int ldsOffB1 = 4096 + (w * 128 + 64 + lane) * 8;

#define STAGE(kb, buf)                                                              \
    do {                                                                            \
        short* bp = &lds[buf][0];                                                   \
        __builtin_amdgcn_global_load_lds(                                           \
            (const __attribute__((address_space(1))) void*)(gA0 + (kb)),            \
            (__attribute__((address_space(3))) void*)(bp + ldsOffA0), 16, 0, 0);    \
        __builtin_amdgcn_global_load_lds(                                           \
            (const __attribute__((address_space(1))) void*)(gA1 + (kb)),            \
            (__attribute__((address_space(3))) void*)(bp + ldsOffA1), 16, 0, 0);    \
        __builtin_amdgcn_global_load_lds(                                           \
            (const __attribute__((address_space(1))) void*)(gB0 + (kb)),            \
            (__attribute__((address_space(3))) void*)(bp + ldsOffB0), 16, 0, 0);    \
        __builtin_amdgcn_global_load_lds(                                           \
            (const __attribute__((address_space(1))) void*)(gB1 + (kb)),            \
            (__attribute__((address_space(3))) void*)(bp + ldsOffB1), 16, 0, 0);    \
    } while (0)

    STAGE(0, 0);

    // ds_read offsets: granule (r, qc) lives at shorts r*32 + (qc ^ ((r>>1)&3))*8;
    // r = wm|wn + s*16 + rsub -> (r>>1)&3 == (rsub>>1)&3.
    const int qz = (q ^ ((rsub >> 1) & 3)) * 8;

    for (int kb = 0; kb < KK; kb += 32) {
        const int cur = (kb >> 5) & 1;
        __syncthreads();  // drains vmcnt: tile kb ready; prev readers done
        if (kb + 32 < KK) STAGE(kb + 32, cur ^ 1);

        const short* bp = &lds[cur][0];
        short8 af[4], bq[4];
#pragma unroll
        for (int s = 0; s < 4; ++s) {
            af[s] = *(const short8*)(bp + (wm + s * 16 + rsub) * 32 + qz);
            bq[s] = *(const short8*)(bp + 4096 + (wn + s * 16 + rsub) * 32 + qz);
        }
#pragma unroll
        for (int s = 0; s < 4; ++s)
#pragma unroll
            for (int n = 0; n < 4; ++n)
                acc[s][n] = __builtin_amdgcn_mfma_f32_16x16x32_bf16(
                    __builtin_bit_cast(bf16x8, af[s]), __builtin_bit_cast(bf16x8, bq[n]),
                    acc[s][n], 0, 0, 0);
    }
#undef STAGE

    // C/D layout: col = lane&15, row = (lane>>4)*4 + reg
    const int rowBase = rowTile + wm + q * 4;
    const int colBase = colTile + wn + rsub;
    if constexpr (MODE == 1) {
        const float beta = *betaPtr;
        short* Sc = (short*)Cout;
        float ncol[4];
#pragma unroll
        for (int n = 0; n < 4; ++n) ncol[n] = sqrtf(nsq[colBase + n * 16]);
#pragma unroll
        for (int s = 0; s < 4; ++s) {
#pragma unroll
            for (int r = 0; r < 4; ++r) {
                const int row = rowBase + s * 16 + r;
                const float nr = sqrtf(nsq[row]);
#pragma unroll
                for (int n = 0; n < 4; ++n) {
                    const int col = colBase + n * 16;
                    float v = acc[s][n][r] * beta / (nr * ncol[n] + EPSV);
                    v += (1.f - adj[(size_t)row * NN + col]) * NEGV;
                    Sc[(size_t)row * NN + col] = f2bf(v);
                }
            }
        }
    } else {
        float* O = (float*)Cout;
#pragma unroll
        for (int s = 0; s < 4; ++s)
#pragma unroll
            for (int r = 0; r < 4; ++r) {
                const int row = rowBase + s * 16 + r;
#pragma unroll
                for (int n = 0; n < 4; ++n)
                    O[(size_t)row * NN + colBase + n * 16] = acc[s][n][r];
            }
    }
}

// In-place row softmax over 4096 bf16 logits; masked entries (-1e9) -> exp = 0.
__global__ __launch_bounds__(256) void softmax_rows(short* __restrict__ S) {
    const int t = threadIdx.x;
    short* rp = S + (size_t)blockIdx.x * NN;
    short8 v0 = ((const short8*)rp)[2 * t];
    short8 v1 = ((const short8*)rp)[2 * t + 1];
    float f[16];
#pragma unroll
    for (int i = 0; i < 8; ++i) {
        f[i] = bf2f(v0[i]);
        f[8 + i] = bf2f(v1[i]);
    }
    float m = f[0];
#pragma unroll
    for (int i = 1; i < 16; ++i) m = fmaxf(m, f[i]);
#pragma unroll
    for (int off = 32; off > 0; off >>= 1) m = fmaxf(m, __shfl_xor(m, off, 64));
    __shared__ float redm[4], reds[4];
    if ((t & 63) == 0) redm[t >> 6] = m;
    __syncthreads();
    m = fmaxf(fmaxf(redm[0], redm[1]), fmaxf(redm[2], redm[3]));
    float sum = 0.f;
#pragma unroll
    for (int i = 0; i < 16; ++i) {
        f[i] = __expf(f[i] - m);
        sum += f[i];
    }
#pragma unroll
    for (int off = 32; off > 0; off >>= 1) sum += __shfl_xor(sum, off, 64);
    if ((t & 63) == 0) reds[t >> 6] = sum;
    __syncthreads();
    sum = reds[0] + reds[1] + reds[2] + reds[3];
    const float rl = 1.f / sum;
    short8 o0, o1;
#pragma unroll
    for (int i = 0; i < 8; ++i) {
        o0[i] = f2bf(f[i] * rl);
        o1[i] = f2bf(f[8 + i] * rl);
    }
    ((short8*)rp)[2 * t] = o0;
    ((short8*)rp)[2 * t + 1] = o1;
}

extern "C" void kernel_launch(void* const* d_in, const int* in_sizes, int n_in,
                              void* d_out, int out_size, void* d_ws, size_t ws_size,
                              hipStream_t stream) {
    const float* x = (const float*)d_in[0];
    const float* adj = (const float*)d_in[1];
    const float* beta = (const float*)d_in[2];

    const size_t MB32 = (size_t)32 * 1024 * 1024;
    if (ws_size < 3 * MB32 + NN * sizeof(float)) return;  // need ~96 MB scratch

    char* ws = (char*)d_ws;
    short* xb = (short*)ws;               // bf16 x          [4096][4096]
    short* xbT = (short*)(ws + MB32);     // bf16 x^T        [4096][4096]
    short* S = (short*)(ws + 2 * MB32);   // bf16 logits / P [4096][4096]
    float* nsq = (float*)(ws + 3 * MB32); // column sumsq    [4096]

    hipMemsetAsync(nsq, 0, NN * sizeof(float), stream);
    col_norm_sq<<<dim3(16, 32), 256, 0, stream>>>(x, nsq);
    cast_transpose<<<dim3(64, 64), dim3(64, 4), 0, stream>>>(x, xb, xbT);
    gemm_nt<1><<<dim3(32, 32), 256, 0, stream>>>(xb, xb, S, nsq, adj, beta);
    softmax_rows<<<NN, 256, 0, stream>>>(S);
    gemm_nt<2><<<dim3(32, 32), 256, 0, stream>>>(S, xbT, d_out, nullptr, nullptr, nullptr);
}

// Round 5
// 474.581 us; speedup vs baseline: 1.4825x; 1.0176x over previous
//
#include <hip/hip_runtime.h>
#include <hip/hip_bf16.h>
#include <stdint.h>

#define NN 4096
#define KK 4096
#define EPSV 1e-7f
#define NEGV -1e9f

typedef short short8 __attribute__((ext_vector_type(8)));
typedef __bf16 bf16x8 __attribute__((ext_vector_type(8)));
typedef float floatx4 __attribute__((ext_vector_type(4)));
typedef float floatx16 __attribute__((ext_vector_type(16)));
typedef int intx4 __attribute__((ext_vector_type(4)));
typedef int intx8 __attribute__((ext_vector_type(8)));

__device__ __forceinline__ float bf2f(short s) {
    union { unsigned u; float f; } c;
    c.u = ((unsigned)(unsigned short)s) << 16;
    return c.f;
}
__device__ __forceinline__ short f2bf(float f) {
    union { float f; unsigned u; } c;
    c.f = f;
    unsigned r = (c.u + 0x7fffu + ((c.u >> 16) & 1u)) >> 16;
    return (short)r;
}

// Fused: read x once -> xf8 (fp8 e4m3, GEMM1), xbT (bf16 x^T, GEMM2), nsq (f32 col sumsq).
__global__ __launch_bounds__(256) void fuse_cast(const float* __restrict__ x,
                                                 unsigned char* __restrict__ xf8,
                                                 short* __restrict__ xbT,
                                                 float* __restrict__ nsq) {
    __shared__ short tile[64][66];  // +2 pad, conflict-free transpose
    __shared__ float csum[4][64];
    const int tx = threadIdx.x;  // 0..63
    const int ty = threadIdx.y;  // 0..3
    const int cb = blockIdx.x * 64;
    const int rb = blockIdx.y * 64;
    float ss = 0.f;
#pragma unroll
    for (int i = 0; i < 16; ++i) {
        int r = ty + i * 4;
        float v = x[(size_t)(rb + r) * NN + cb + tx];
        ss = fmaf(v, v, ss);
        tile[r][tx] = f2bf(v);
        int pk = __builtin_amdgcn_cvt_pk_fp8_f32(v, v, 0, false);
        xf8[(size_t)(rb + r) * NN + cb + tx] = (unsigned char)(pk & 0xff);
    }
    csum[ty][tx] = ss;
    __syncthreads();
    if (ty == 0)
        atomicAdd(&nsq[cb + tx], csum[0][tx] + csum[1][tx] + csum[2][tx] + csum[3][tx]);
#pragma unroll
    for (int i = 0; i < 16; ++i) {
        int r = ty + i * 4;
        xbT[(size_t)(cb + r) * NN + rb + tx] = tile[tx][r];
    }
}

// GEMM1, fp8: S[i][j] = mask/scale( sum_k x8[i][k]*x8[j][k] ).  128x128 tile,
// BK=64, 4 waves 2x2, each wave 64x64 via 2x2 mfma_scale_f32_32x32x64_f8f6f4
// with unit e8m0 scales (127 = 2^0) -> plain fp8 at 2x bf16 MFMA rate, half
// the staged bytes, half the K-iterations (half the barrier-drain stalls).
// LDS layout: [row][64B], 16B granule at position c ^ s(row),
// s(row)=row<1>|row<3><<1 -> every ds_read_b128 lands uniform 8 lanes/bank-quad
// (conflict-free) and glds keeps 4-lane/64B-line global coalescing.
// A-frag layout: A[m=lane&31][k=(lane>>5)*32 + byte 0..31]; C/D per m101.
__global__ __launch_bounds__(256, 3) void gemm_f8(const unsigned char* __restrict__ X8,
                                                  short* __restrict__ Sc,
                                                  const float* __restrict__ nsq,
                                                  const float* __restrict__ adj,
                                                  const float* __restrict__ betaPtr) {
    __shared__ __align__(16) char lds[2][16384];  // [buf][A 8KB | B 8KB]

    const int t = threadIdx.x;
    const int lane = t & 63;
    const int w = t >> 6;
    const int rowTile = blockIdx.y * 128;
    const int colTile = blockIdx.x * 128;
    const int wm = (w >> 1) * 64;
    const int wn = (w & 1) * 64;

    floatx16 acc[2][2];
#pragma unroll
    for (int mt = 0; mt < 2; ++mt)
#pragma unroll
        for (int nt = 0; nt < 2; ++nt)
#pragma unroll
            for (int r = 0; r < 16; ++r) acc[mt][nt][r] = 0.f;

    // staging: wave w stages rows [w*32, w*32+32) of A and B halves.
    // lane -> row w*32 + (lane>>2) (+16 for second call), content chunk
    // qsw = (lane&3) ^ s(row); s(row) bits = lane bits 3 and 5 here.
    const int qsw = (lane & 3) ^ (((lane >> 3) & 1) | (((lane >> 5) & 1) << 1));
    const int ra = w * 32 + (lane >> 2);
    const unsigned char* gA0 = X8 + (size_t)(rowTile + ra) * KK + qsw * 16;
    const unsigned char* gA1 = gA0 + (size_t)16 * KK;
    const unsigned char* gB0 = X8 + (size_t)(colTile + ra) * KK + qsw * 16;
    const unsigned char* gB1 = gB0 + (size_t)16 * KK;
    const int loA0 = (w * 128 + lane) * 16;
    const int loA1 = loA0 + 1024;
    const int loB0 = 8192 + (w * 128 + lane) * 16;
    const int loB1 = loB0 + 1024;

#define STAGE8(kb, buf)                                                           \
    do {                                                                          \
        char* bp_ = &lds[buf][0];                                                 \
        __builtin_amdgcn_global_load_lds(                                         \
            (const __attribute__((address_space(1))) void*)(gA0 + (kb)),          \
            (__attribute__((address_space(3))) void*)(bp_ + loA0), 16, 0, 0);     \
        __builtin_amdgcn_global_load_lds(                                         \
            (const __attribute__((address_space(1))) void*)(gA1 + (kb)),          \
            (__attribute__((address_space(3))) void*)(bp_ + loA1), 16, 0, 0);     \
        __builtin_amdgcn_global_load_lds(                                         \
            (const __attribute__((address_space(1))) void*)(gB0 + (kb)),          \
            (__attribute__((address_space(3))) void*)(bp_ + loB0), 16, 0, 0);     \
        __builtin_amdgcn_global_load_lds(                                         \
            (const __attribute__((address_space(1))) void*)(gB1 + (kb)),          \
            (__attribute__((address_space(3))) void*)(bp_ + loB1), 16, 0, 0);     \
    } while (0)

    STAGE8(0, 0);

    // frag read positions: lane reads k-bytes (lane>>5)*32 + [0..32) of its row
    // = content chunks cLo=(lane>>5)*2, cLo+1 at swizzled positions c ^ sR.
    const int m31 = lane & 31;
    const int sR = ((lane >> 1) & 1) | (((lane >> 3) & 1) << 1);
    const int posLo = ((lane >> 5) * 2) ^ sR;
    const int posHi = ((lane >> 5) * 2 + 1) ^ sR;

    for (int kb = 0; kb < KK; kb += 64) {
        const int cur = (kb >> 6) & 1;
        __syncthreads();  // tile kb staged; prev buf's readers done
        if (kb + 64 < KK) STAGE8(kb + 64, cur ^ 1);

        const char* bp = &lds[cur][0];
        intx8 af[2], bfr[2];
#pragma unroll
        for (int mt = 0; mt < 2; ++mt) {
            const int rA = wm + mt * 32 + m31;
            intx4 lo = *(const intx4*)(bp + (rA * 4 + posLo) * 16);
            intx4 hi = *(const intx4*)(bp + (rA * 4 + posHi) * 16);
            af[mt] = __builtin_shufflevector(lo, hi, 0, 1, 2, 3, 4, 5, 6, 7);
            const int rB = wn + mt * 32 + m31;
            intx4 blo = *(const intx4*)(bp + 8192 + (rB * 4 + posLo) * 16);
            intx4 bhi = *(const intx4*)(bp + 8192 + (rB * 4 + posHi) * 16);
            bfr[mt] = __builtin_shufflevector(blo, bhi, 0, 1, 2, 3, 4, 5, 6, 7);
        }
#pragma unroll
        for (int mt = 0; mt < 2; ++mt)
#pragma unroll
            for (int nt = 0; nt < 2; ++nt)
                acc[mt][nt] = __builtin_amdgcn_mfma_scale_f32_32x32x64_f8f6f4(
                    af[mt], bfr[nt], acc[mt][nt], 0, 0,  // cbsz=fp8, blgp=fp8
                    0, 127, 0, 127);                     // unit e8m0 scales
    }
#undef STAGE8

    // C/D (32x32): col = lane&31, row = (reg&3) + 8*(reg>>2) + 4*(lane>>5)
    const float beta = *betaPtr;
    const int kh = lane >> 5;
    float nc2[2];
#pragma unroll
    for (int nt = 0; nt < 2; ++nt) nc2[nt] = sqrtf(nsq[colTile + wn + nt * 32 + m31]);
#pragma unroll
    for (int mt = 0; mt < 2; ++mt) {
        const int rbase = rowTile + wm + mt * 32 + 4 * kh;
#pragma unroll
        for (int reg = 0; reg < 16; ++reg) {
            const int row = rbase + (reg & 3) + 8 * (reg >> 2);
            const float nr = sqrtf(nsq[row]);
#pragma unroll
            for (int nt = 0; nt < 2; ++nt) {
                const int col = colTile + wn + nt * 32 + m31;
                float v = acc[mt][nt][reg] * beta / (nr * nc2[nt] + EPSV);
                v += (1.f - adj[(size_t)row * NN + col]) * NEGV;
                Sc[(size_t)row * NN + col] = f2bf(v);
            }
        }
    }
}

// GEMM2 (bf16, proven R3 structure): out[i][d] = sum_j P[i][j] * xbT[d][j]
__global__ __launch_bounds__(256, 4) void gemm_bf16(const short* __restrict__ A,
                                                    const short* __restrict__ Bt,
                                                    float* __restrict__ O) {
    __shared__ __align__(16) short lds[2][8192];

    const int t = threadIdx.x;
    const int rowTile = blockIdx.y * 128;
    const int colTile = blockIdx.x * 128;

    floatx4 acc[4][4];
#pragma unroll
    for (int s = 0; s < 4; ++s)
#pragma unroll
        for (int n = 0; n < 4; ++n) acc[s][n] = (floatx4){0.f, 0.f, 0.f, 0.f};

    const int lane = t & 63;
    const int w = t >> 6;
    const int wm = (w >> 1) * 64;
    const int wn = (w & 1) * 64;
    const int q = lane >> 4;
    const int rsub = lane & 15;

    const int qsw = (lane & 3) ^ ((lane >> 3) & 3);
    const int srow = w * 32 + (lane >> 2);
    const short* gA0 = A + (size_t)(rowTile + srow) * KK + qsw * 8;
    const short* gA1 = A + (size_t)(rowTile + srow + 16) * KK + qsw * 8;
    const short* gB0 = Bt + (size_t)(colTile + srow) * KK + qsw * 8;
    const short* gB1 = Bt + (size_t)(colTile + srow + 16) * KK + qsw * 8;
    const int ldsOffA0 = (w * 128 + lane) * 8;
    const int ldsOffA1 = (w * 128 + 64 + lane) * 8;
    const int ldsOffB0 = 4096 + (w * 128 + lane) * 8;
    const int ldsOffB1 = 4096 + (w * 128 + 64 + lane) * 8;

#define STAGE(kb, buf)                                                              \
    do {                                                                            \
        short* bp = &lds[buf][0];                                                   \
        __builtin_amdgcn_global_load_lds(                                           \
            (const __attribute__((address_space(1))) void*)(gA0 + (kb)),            \
            (__attribute__((address_space(3))) void*)(bp + ldsOffA0), 16, 0, 0);    \
        __builtin_amdgcn_global_load_lds(                                           \
            (const __attribute__((address_space(1))) void*)(gA1 + (kb)),            \
            (__attribute__((address_space(3))) void*)(bp + ldsOffA1), 16, 0, 0);    \
        __builtin_amdgcn_global_load_lds(                                           \
            (const __attribute__((address_space(1))) void*)(gB0 + (kb)),            \
            (__attribute__((address_space(3))) void*)(bp + ldsOffB0), 16, 0, 0);    \
        __builtin_amdgcn_global_load_lds(                                           \
            (const __attribute__((address_space(1))) void*)(gB1 + (kb)),            \
            (__attribute__((address_space(3))) void*)(bp + ldsOffB1), 16, 0, 0);    \
    } while (0)

    STAGE(0, 0);
    const int qz = (q ^ ((rsub >> 1) & 3)) * 8;

    for (int kb = 0; kb < KK; kb += 32) {
        const int cur = (kb >> 5) & 1;
        __syncthreads();
        if (kb + 32 < KK) STAGE(kb + 32, cur ^ 1);

        const short* bp = &lds[cur][0];
        short8 af[4], bq[4];
#pragma unroll
        for (int s = 0; s < 4; ++s) {
            af[s] = *(const short8*)(bp + (wm + s * 16 + rsub) * 32 + qz);
            bq[s] = *(const short8*)(bp + 4096 + (wn + s * 16 + rsub) * 32 + qz);
        }
#pragma unroll
        for (int s = 0; s < 4; ++s)
#pragma unroll
            for (int n = 0; n < 4; ++n)
                acc[s][n] = __builtin_amdgcn_mfma_f32_16x16x32_bf16(
                    __builtin_bit_cast(bf16x8, af[s]), __builtin_bit_cast(bf16x8, bq[n]),
                    acc[s][n], 0, 0, 0);
    }
#undef STAGE

    const int rowBase = rowTile + wm + q * 4;
    const int colBase = colTile + wn + rsub;
#pragma unroll
    for (int s = 0; s < 4; ++s)
#pragma unroll
        for (int r = 0; r < 4; ++r) {
            const int row = rowBase + s * 16 + r;
#pragma unroll
            for (int n = 0; n < 4; ++n)
                O[(size_t)row * NN + colBase + n * 16] = acc[s][n][r];
        }
}

// In-place row softmax over 4096 bf16 logits; masked entries (-1e9) -> exp = 0.
__global__ __launch_bounds__(256) void softmax_rows(short* __restrict__ S) {
    const int t = threadIdx.x;
    short* rp = S + (size_t)blockIdx.x * NN;
    short8 v0 = ((const short8*)rp)[2 * t];
    short8 v1 = ((const short8*)rp)[2 * t + 1];
    float f[16];
#pragma unroll
    for (int i = 0; i < 8; ++i) {
        f[i] = bf2f(v0[i]);
        f[8 + i] = bf2f(v1[i]);
    }
    float m = f[0];
#pragma unroll
    for (int i = 1; i < 16; ++i) m = fmaxf(m, f[i]);
#pragma unroll
    for (int off = 32; off > 0; off >>= 1) m = fmaxf(m, __shfl_xor(m, off, 64));
    __shared__ float redm[4], reds[4];
    if ((t & 63) == 0) redm[t >> 6] = m;
    __syncthreads();
    m = fmaxf(fmaxf(redm[0], redm[1]), fmaxf(redm[2], redm[3]));
    float sum = 0.f;
#pragma unroll
    for (int i = 0; i < 16; ++i) {
        f[i] = __expf(f[i] - m);
        sum += f[i];
    }
#pragma unroll
    for (int off = 32; off > 0; off >>= 1) sum += __shfl_xor(sum, off, 64);
    if ((t & 63) == 0) reds[t >> 6] = sum;
    __syncthreads();
    sum = reds[0] + reds[1] + reds[2] + reds[3];
    const float rl = 1.f / sum;
    short8 o0, o1;
#pragma unroll
    for (int i = 0; i < 8; ++i) {
        o0[i] = f2bf(f[i] * rl);
        o1[i] = f2bf(f[8 + i] * rl);
    }
    ((short8*)rp)[2 * t] = o0;
    ((short8*)rp)[2 * t + 1] = o1;
}

extern "C" void kernel_launch(void* const* d_in, const int* in_sizes, int n_in,
                              void* d_out, int out_size, void* d_ws, size_t ws_size,
                              hipStream_t stream) {
    const float* x = (const float*)d_in[0];
    const float* adj = (const float*)d_in[1];
    const float* beta = (const float*)d_in[2];

    const size_t MB32 = (size_t)32 * 1024 * 1024;
    const size_t MB16 = (size_t)16 * 1024 * 1024;
    if (ws_size < 2 * MB32 + MB16 + NN * sizeof(float)) return;  // ~80 MB

    char* ws = (char*)d_ws;
    short* xbT = (short*)ws;                         // bf16 x^T        32 MB
    short* S = (short*)(ws + MB32);                  // bf16 logits / P 32 MB
    unsigned char* xf8 = (unsigned char*)(ws + 2 * MB32);  // fp8 x    16 MB
    float* nsq = (float*)(ws + 2 * MB32 + MB16);     // col sumsq       16 KB

    (void)hipMemsetAsync(nsq, 0, NN * sizeof(float), stream);
    fuse_cast<<<dim3(64, 64), dim3(64, 4), 0, stream>>>(x, xf8, xbT, nsq);
    gemm_f8<<<dim3(32, 32), 256, 0, stream>>>(xf8, S, nsq, adj, beta);
    softmax_rows<<<NN, 256, 0, stream>>>(S);
    gemm_bf16<<<dim3(32, 32), 256, 0, stream>>>(S, xbT, (float*)d_out);
}